// Round 5
// baseline (180.076 us; speedup 1.0000x reference)
//
#include <hip/hip_runtime.h>

#define BATCH 16
#define HH 512
#define WW 512
#define NPIX (BATCH * HH * WW)

#define RAD 4
#define OT 32              // output tile (32x32)
#define MT (OT + 2*RAD)    // 40: m/t intermediate region
#define ST (MT + 2*RAD)    // 48: s/q input tile

// ---------------------------------------------------------------------------
// Kernel 0: normalize the 9x9 filter: f = (filt + 10) / sum(filt + 10)
// ---------------------------------------------------------------------------
__global__ void norm_filter_kernel(const float* __restrict__ filt,
                                   float* __restrict__ f) {
    __shared__ float sh[128];
    int tid = threadIdx.x;
    float v = (tid < 81) ? (filt[tid] + 10.0f) : 0.0f;
    sh[tid] = v;
    __syncthreads();
    for (int o = 64; o > 0; o >>= 1) {
        if (tid < o) sh[tid] += sh[tid + o];
        __syncthreads();
    }
    float sum = sh[0];
    if (tid < 81) f[tid] = v / sum;
}

// ---------------------------------------------------------------------------
// Fused conv kernel, per 32x32 output tile.
//   staging: s = sum_c x, q = sum_c x^2 on 48x48 halo tile (zero-padded)
//   phase 1: m = conv(s,f) on 40x40; t = q - 2ms + 3m^2 (0 outside image)
//            into LDS; write m for inner 32x32
//   phase 2: sigma = sqrt(conv(t,f)) on 32x32; write sigma + partial sum
// Filter taps come from GLOBAL memory with uniform compile-const indices
// (scalar s_load path, zero LDS/VALU cost). All tile reads are ds_read_b128.
// ---------------------------------------------------------------------------
__global__ __launch_bounds__(256) void lcn_fused_kernel(
        const float* __restrict__ x, const float* __restrict__ f,
        float* __restrict__ m, float* __restrict__ sig,
        float* __restrict__ partial) {
    __shared__ float s48[ST][ST];
    __shared__ float q48[ST][ST];
    __shared__ float t40[MT][MT];
    __shared__ float wsum[4];

    const int tid = threadIdx.x;
    const int b = blockIdx.z;
    const int h0 = blockIdx.y * OT;
    const int w0 = blockIdx.x * OT;
    const float* xb = x + (size_t)b * HH * WW * 3;

    // ---- staging: 48x48 = 2304 px = 9 exact rounds of 256
#pragma unroll
    for (int k = 0; k < 9; k++) {
        const int i = tid + k * 256;
        const int r = i / ST, c = i - r * ST;
        const int gh = h0 - 2 * RAD + r, gw = w0 - 2 * RAD + c;
        float sv = 0.0f, qv = 0.0f;
        if (gh >= 0 && gh < HH && gw >= 0 && gw < WW) {
            const float* xp = xb + ((size_t)gh * WW + gw) * 3;
            float a0 = xp[0], a1 = xp[1], a2 = xp[2];
            sv = a0 + a1 + a2;
            qv = a0 * a0 + a1 * a1 + a2 * a2;
        }
        s48[r][c] = sv;
        q48[r][c] = qv;
    }
    __syncthreads();

    // ---- phase 1: m over 40x40 (10 col-groups x 40 rows = 400 items)
    for (int item = tid; item < MT * (MT / 4); item += 256) {
        const int cg = item % (MT / 4);       // 0..9
        const int row = item / (MT / 4);      // 0..39
        const int c0 = 4 * cg;

        float acc0 = 0.f, acc1 = 0.f, acc2 = 0.f, acc3 = 0.f;
#pragma unroll
        for (int dh = 0; dh < 9; dh++) {
            const float4 va = *(const float4*)&s48[row + dh][c0];
            const float4 vb = *(const float4*)&s48[row + dh][c0 + 4];
            const float4 vc = *(const float4*)&s48[row + dh][c0 + 8];
            const float v[12] = {va.x, va.y, va.z, va.w,
                                 vb.x, vb.y, vb.z, vb.w,
                                 vc.x, vc.y, vc.z, vc.w};
#pragma unroll
            for (int j = 0; j < 9; j++) {
                const float fv = f[dh * 9 + j];   // uniform -> s_load
                acc0 += v[j] * fv;
                acc1 += v[j + 1] * fv;
                acc2 += v[j + 2] * fv;
                acc3 += v[j + 3] * fv;
            }
        }

        // centers for t = q - 2 m s + 3 m^2
        const float4 sc = *(const float4*)&s48[row + 4][c0 + 4];
        const float4 qc = *(const float4*)&q48[row + 4][c0 + 4];
        const int gh = h0 - RAD + row;
        const bool ghin = (gh >= 0 && gh < HH);
        const int gw0 = w0 - RAD + c0;
        float4 tv;
        tv.x = (ghin && gw0 + 0 >= 0 && gw0 + 0 < WW)
                   ? qc.x - 2.0f * acc0 * sc.x + 3.0f * acc0 * acc0 : 0.0f;
        tv.y = (ghin && gw0 + 1 >= 0 && gw0 + 1 < WW)
                   ? qc.y - 2.0f * acc1 * sc.y + 3.0f * acc1 * acc1 : 0.0f;
        tv.z = (ghin && gw0 + 2 >= 0 && gw0 + 2 < WW)
                   ? qc.z - 2.0f * acc2 * sc.z + 3.0f * acc2 * acc2 : 0.0f;
        tv.w = (ghin && gw0 + 3 >= 0 && gw0 + 3 < WW)
                   ? qc.w - 2.0f * acc3 * sc.w + 3.0f * acc3 * acc3 : 0.0f;
        *(float4*)&t40[row][c0] = tv;

        // write m for the inner 32x32 (rows 4..35, col-groups 1..8)
        if (row >= RAD && row < RAD + OT && cg >= 1 && cg <= 8) {
            float4 mv4 = {acc0, acc1, acc2, acc3};
            *(float4*)&m[((size_t)b * HH + gh) * WW + (w0 + 4 * (cg - 1))] = mv4;
        }
    }
    __syncthreads();

    // ---- phase 2: sigma over 32x32 (8 col-groups x 32 rows = 256 exact)
    float psum = 0.0f;
    {
        const int cg = tid % (OT / 4);        // 0..7
        const int row = tid / (OT / 4);       // 0..31
        const int c0 = 4 * cg;

        float acc0 = 0.f, acc1 = 0.f, acc2 = 0.f, acc3 = 0.f;
#pragma unroll
        for (int dh = 0; dh < 9; dh++) {
            const float4 va = *(const float4*)&t40[row + dh][c0];
            const float4 vb = *(const float4*)&t40[row + dh][c0 + 4];
            const float4 vc = *(const float4*)&t40[row + dh][c0 + 8];
            const float v[12] = {va.x, va.y, va.z, va.w,
                                 vb.x, vb.y, vb.z, vb.w,
                                 vc.x, vc.y, vc.z, vc.w};
#pragma unroll
            for (int j = 0; j < 9; j++) {
                const float fv = f[dh * 9 + j];   // uniform -> s_load
                acc0 += v[j] * fv;
                acc1 += v[j + 1] * fv;
                acc2 += v[j + 2] * fv;
                acc3 += v[j + 3] * fv;
            }
        }
        float4 sg;
        sg.x = sqrtf(fmaxf(acc0, 0.0f));
        sg.y = sqrtf(fmaxf(acc1, 0.0f));
        sg.z = sqrtf(fmaxf(acc2, 0.0f));
        sg.w = sqrtf(fmaxf(acc3, 0.0f));
        *(float4*)&sig[((size_t)b * HH + (h0 + row)) * WW + (w0 + c0)] = sg;
        psum = sg.x + sg.y + sg.z + sg.w;
    }

    // ---- block partial sum (private slot per block; no atomics)
#pragma unroll
    for (int o = 32; o > 0; o >>= 1) psum += __shfl_down(psum, o);
    if ((tid & 63) == 0) wsum[tid >> 6] = psum;
    __syncthreads();
    if (tid == 0)
        partial[b * 256 + blockIdx.y * 16 + blockIdx.x] =
            wsum[0] + wsum[1] + wsum[2] + wsum[3];
}

// ---------------------------------------------------------------------------
// Reduce 256 partials per batch -> bsum[b]
// ---------------------------------------------------------------------------
__global__ __launch_bounds__(256) void reduce_bsum_kernel(
        const float* __restrict__ partial, float* __restrict__ bsum) {
    __shared__ float wsum[4];
    const int b = blockIdx.x, tid = threadIdx.x;
    float v = partial[b * 256 + tid];
#pragma unroll
    for (int o = 32; o > 0; o >>= 1) v += __shfl_down(v, o);
    if ((tid & 63) == 0) wsum[tid >> 6] = v;
    __syncthreads();
    if (tid == 0) bsum[b] = wsum[0] + wsum[1] + wsum[2] + wsum[3];
}

// ---------------------------------------------------------------------------
// Final: out = (x - m) * rcp(max(mean_b, sigma)); 4 pixels / thread
// ---------------------------------------------------------------------------
__global__ __launch_bounds__(256) void final_kernel(
        const float* __restrict__ x, const float* __restrict__ m,
        const float* __restrict__ sig, const float* __restrict__ bsum,
        float* __restrict__ out) {
    const int i = blockIdx.x * 256 + threadIdx.x;   // group of 4 pixels
    const int b = i >> 16;                          // (i*4) / (512*512)
    const float mean = bsum[b] * (1.0f / (HH * WW));

    float4 mv = ((const float4*)m)[i];
    float4 sv = ((const float4*)sig)[i];
    const float4* xp = (const float4*)x + (size_t)i * 3;
    float4 a = xp[0], bb = xp[1], cc = xp[2];

    // one reciprocal per pixel (v_rcp_f32; rel err ~1e-7, threshold is 6e-2)
    float r0 = __builtin_amdgcn_rcpf(fmaxf(mean, sv.x));
    float r1 = __builtin_amdgcn_rcpf(fmaxf(mean, sv.y));
    float r2 = __builtin_amdgcn_rcpf(fmaxf(mean, sv.z));
    float r3 = __builtin_amdgcn_rcpf(fmaxf(mean, sv.w));

    float4 o0, o1, o2;
    o0.x = (a.x - mv.x) * r0;
    o0.y = (a.y - mv.x) * r0;
    o0.z = (a.z - mv.x) * r0;
    o0.w = (a.w - mv.y) * r1;
    o1.x = (bb.x - mv.y) * r1;
    o1.y = (bb.y - mv.y) * r1;
    o1.z = (bb.z - mv.z) * r2;
    o1.w = (bb.w - mv.z) * r2;
    o2.x = (cc.x - mv.z) * r2;
    o2.y = (cc.y - mv.w) * r3;
    o2.z = (cc.z - mv.w) * r3;
    o2.w = (cc.w - mv.w) * r3;

    float4* op = (float4*)out + (size_t)i * 3;
    op[0] = o0;
    op[1] = o1;
    op[2] = o2;
}

// ---------------------------------------------------------------------------
extern "C" void kernel_launch(void* const* d_in, const int* in_sizes, int n_in,
                              void* d_out, int out_size, void* d_ws, size_t ws_size,
                              hipStream_t stream) {
    const float* x = (const float*)d_in[0];
    const float* filt = (const float*)d_in[1];
    float* out = (float*)d_out;

    char* ws = (char*)d_ws;
    float* f = (float*)ws;                          // 81 floats
    float* bsum = (float*)(ws + 512);               // 16 floats
    float* partial = (float*)(ws + 1024);           // 4096 floats
    float* m = (float*)(ws + 32768);                // NPIX floats (16.8 MB)
    float* sig = m + NPIX;                          // NPIX floats

    norm_filter_kernel<<<1, 128, 0, stream>>>(filt, f);

    dim3 cgrid(WW / OT, HH / OT, BATCH);            // (16, 16, 16)
    lcn_fused_kernel<<<cgrid, 256, 0, stream>>>(x, f, m, sig, partial);
    reduce_bsum_kernel<<<BATCH, 256, 0, stream>>>(partial, bsum);
    final_kernel<<<NPIX / 4 / 256, 256, 0, stream>>>(x, m, sig, bsum, out);
}

// Round 6
// 156.986 us; speedup vs baseline: 1.1471x; 1.1471x over previous
//
#include <hip/hip_runtime.h>

#define BATCH 16
#define HH 512
#define WW 512
#define NPIX (BATCH * HH * WW)

#define TW 32          // threads x = output tile width
#define TH 8           // threads y
#define ROWS 4         // output rows per thread
#define OTH (TH*ROWS)  // 32 = output tile height
#define RAD 4
#define LW (TW + 2 * RAD)   // 40
#define LH (OTH + 2 * RAD)  // 40

// ---------------------------------------------------------------------------
// Kernel 0: normalize the 9x9 filter: f = (filt + 10) / sum(filt + 10)
// ---------------------------------------------------------------------------
__global__ void norm_filter_kernel(const float* __restrict__ filt,
                                   float* __restrict__ f) {
    __shared__ float sh[128];
    int tid = threadIdx.x;
    float v = (tid < 81) ? (filt[tid] + 10.0f) : 0.0f;
    sh[tid] = v;
    __syncthreads();
    for (int o = 64; o > 0; o >>= 1) {
        if (tid < o) sh[tid] += sh[tid + o];
        __syncthreads();
    }
    float sum = sh[0];
    if (tid < 81) f[tid] = v / sum;
}

// ---------------------------------------------------------------------------
// Kernel 1: fused channel-sum + conv -> local mean m, and t = sum_c (x_c-m)^2
// 32x32 tile; 4 rows/thread sliding window; scalar b32 LDS reads (stride 40,
// tx-consecutive => measured conflict-free). Filter taps f[dh*9+j] read from
// GLOBAL with compile-const uniform indices -> hoisted to SGPRs (no LDS).
// ---------------------------------------------------------------------------
__global__ __launch_bounds__(256) void conv_mean_kernel(
        const float* __restrict__ x, const float* __restrict__ f,
        float* __restrict__ m, float* __restrict__ t) {
    __shared__ float tile[LH][LW];

    const int tx = threadIdx.x, ty = threadIdx.y;
    const int tid = ty * TW + tx;
    const int b = blockIdx.z;
    const int h0 = blockIdx.y * OTH;
    const int w0 = blockIdx.x * TW;
    const float* xb = x + (size_t)b * HH * WW * 3;

    // cooperative halo load: channel-sum of x, zero outside (SAME padding)
    for (int i = tid; i < LH * LW; i += 256) {
        int r = i / LW, c = i - r * LW;
        int gh = h0 - RAD + r, gw = w0 - RAD + c;
        float v = 0.0f;
        if (gh >= 0 && gh < HH && gw >= 0 && gw < WW) {
            const float* xp = xb + ((size_t)gh * WW + gw) * 3;
            v = xp[0] + xp[1] + xp[2];
        }
        tile[r][c] = v;
    }
    __syncthreads();

    const int r0 = ty * ROWS;
    float acc[ROWS] = {0.f, 0.f, 0.f, 0.f};
#pragma unroll
    for (int tr = 0; tr < ROWS + 8; tr++) {
        float v[9];
#pragma unroll
        for (int j = 0; j < 9; j++) v[j] = tile[r0 + tr][tx + j];
#pragma unroll
        for (int o = 0; o < ROWS; o++) {
            const int dh = tr - o;
            if (dh >= 0 && dh < 9) {
#pragma unroll
                for (int j = 0; j < 9; j++) acc[o] += v[j] * f[dh * 9 + j];
            }
        }
    }

#pragma unroll
    for (int o = 0; o < ROWS; o++) {
        const int h = h0 + r0 + o, w = w0 + tx;
        const size_t idx = ((size_t)b * HH + h) * WW + w;
        m[idx] = acc[o];
        const float* xp = xb + ((size_t)h * WW + w) * 3;
        float d0 = xp[0] - acc[o];
        float d1 = xp[1] - acc[o];
        float d2 = xp[2] - acc[o];
        t[idx] = d0 * d0 + d1 * d1 + d2 * d2;
    }
}

// ---------------------------------------------------------------------------
// Kernel 2: conv(t, f) -> sigma = sqrt(.), per-block partial sums (NO atomics)
// ---------------------------------------------------------------------------
__global__ __launch_bounds__(256) void conv_sigma_kernel(
        const float* __restrict__ t, const float* __restrict__ f,
        float* __restrict__ sig, float* __restrict__ partial) {
    __shared__ float tile[LH][LW];
    __shared__ float wsum[4];

    const int tx = threadIdx.x, ty = threadIdx.y;
    const int tid = ty * TW + tx;
    const int b = blockIdx.z;
    const int h0 = blockIdx.y * OTH;
    const int w0 = blockIdx.x * TW;
    const float* tb = t + (size_t)b * HH * WW;

    for (int i = tid; i < LH * LW; i += 256) {
        int r = i / LW, c = i - r * LW;
        int gh = h0 - RAD + r, gw = w0 - RAD + c;
        float v = 0.0f;
        if (gh >= 0 && gh < HH && gw >= 0 && gw < WW) {
            v = tb[(size_t)gh * WW + gw];
        }
        tile[r][c] = v;
    }
    __syncthreads();

    const int r0 = ty * ROWS;
    float acc[ROWS] = {0.f, 0.f, 0.f, 0.f};
#pragma unroll
    for (int tr = 0; tr < ROWS + 8; tr++) {
        float v[9];
#pragma unroll
        for (int j = 0; j < 9; j++) v[j] = tile[r0 + tr][tx + j];
#pragma unroll
        for (int o = 0; o < ROWS; o++) {
            const int dh = tr - o;
            if (dh >= 0 && dh < 9) {
#pragma unroll
                for (int j = 0; j < 9; j++) acc[o] += v[j] * f[dh * 9 + j];
            }
        }
    }

    float psum = 0.0f;
#pragma unroll
    for (int o = 0; o < ROWS; o++) {
        float sg = sqrtf(fmaxf(acc[o], 0.0f));
        const int h = h0 + r0 + o, w = w0 + tx;
        sig[((size_t)b * HH + h) * WW + w] = sg;
        psum += sg;
    }

    // block reduction -> one private partial slot per block (no contention)
#pragma unroll
    for (int o = 32; o > 0; o >>= 1) psum += __shfl_down(psum, o);
    if ((tid & 63) == 0) wsum[tid >> 6] = psum;
    __syncthreads();
    if (tid == 0)
        partial[b * 256 + blockIdx.y * 16 + blockIdx.x] =
            wsum[0] + wsum[1] + wsum[2] + wsum[3];
}

// ---------------------------------------------------------------------------
// Kernel 2.5: reduce 256 partials per batch -> bsum[b]
// ---------------------------------------------------------------------------
__global__ __launch_bounds__(256) void reduce_bsum_kernel(
        const float* __restrict__ partial, float* __restrict__ bsum) {
    __shared__ float wsum[4];
    const int b = blockIdx.x, tid = threadIdx.x;
    float v = partial[b * 256 + tid];
#pragma unroll
    for (int o = 32; o > 0; o >>= 1) v += __shfl_down(v, o);
    if ((tid & 63) == 0) wsum[tid >> 6] = v;
    __syncthreads();
    if (tid == 0) bsum[b] = wsum[0] + wsum[1] + wsum[2] + wsum[3];
}

// ---------------------------------------------------------------------------
// Kernel 3: out = (x - m) * rcp(max(mean_b, sigma)); 4 pixels / thread
// ---------------------------------------------------------------------------
__global__ __launch_bounds__(256) void final_kernel(
        const float* __restrict__ x, const float* __restrict__ m,
        const float* __restrict__ sig, const float* __restrict__ bsum,
        float* __restrict__ out) {
    const int i = blockIdx.x * 256 + threadIdx.x;   // group of 4 pixels
    const int b = i >> 16;                          // (i*4) / (512*512)
    const float mean = bsum[b] * (1.0f / (HH * WW));

    float4 mv = ((const float4*)m)[i];
    float4 sv = ((const float4*)sig)[i];
    const float4* xp = (const float4*)x + (size_t)i * 3;
    float4 a = xp[0], bb = xp[1], cc = xp[2];

    // one reciprocal per pixel (v_rcp_f32; rel err ~1e-7, threshold is 6e-2)
    float r0 = __builtin_amdgcn_rcpf(fmaxf(mean, sv.x));
    float r1 = __builtin_amdgcn_rcpf(fmaxf(mean, sv.y));
    float r2 = __builtin_amdgcn_rcpf(fmaxf(mean, sv.z));
    float r3 = __builtin_amdgcn_rcpf(fmaxf(mean, sv.w));

    float4 o0, o1, o2;
    o0.x = (a.x - mv.x) * r0;
    o0.y = (a.y - mv.x) * r0;
    o0.z = (a.z - mv.x) * r0;
    o0.w = (a.w - mv.y) * r1;
    o1.x = (bb.x - mv.y) * r1;
    o1.y = (bb.y - mv.y) * r1;
    o1.z = (bb.z - mv.z) * r2;
    o1.w = (bb.w - mv.z) * r2;
    o2.x = (cc.x - mv.z) * r2;
    o2.y = (cc.y - mv.w) * r3;
    o2.z = (cc.z - mv.w) * r3;
    o2.w = (cc.w - mv.w) * r3;

    float4* op = (float4*)out + (size_t)i * 3;
    op[0] = o0;
    op[1] = o1;
    op[2] = o2;
}

// ---------------------------------------------------------------------------
extern "C" void kernel_launch(void* const* d_in, const int* in_sizes, int n_in,
                              void* d_out, int out_size, void* d_ws, size_t ws_size,
                              hipStream_t stream) {
    const float* x = (const float*)d_in[0];
    const float* filt = (const float*)d_in[1];
    float* out = (float*)d_out;

    char* ws = (char*)d_ws;
    float* f = (float*)ws;                          // 81 floats
    float* bsum = (float*)(ws + 512);               // 16 floats
    float* partial = (float*)(ws + 1024);           // 4096 floats
    float* m = (float*)(ws + 32768);                // NPIX floats (16.8 MB)
    float* t = m + NPIX;                            // NPIX floats
    float* sig = t + NPIX;                          // NPIX floats

    norm_filter_kernel<<<1, 128, 0, stream>>>(filt, f);

    dim3 cblock(TW, TH);
    dim3 cgrid(WW / TW, HH / OTH, BATCH);           // (16, 16, 16)
    conv_mean_kernel<<<cgrid, cblock, 0, stream>>>(x, f, m, t);
    conv_sigma_kernel<<<cgrid, cblock, 0, stream>>>(t, f, sig, partial);
    reduce_bsum_kernel<<<BATCH, 256, 0, stream>>>(partial, bsum);

    final_kernel<<<NPIX / 4 / 256, 256, 0, stream>>>(x, m, sig, bsum, out);
}